// Round 12
// baseline (120.903 us; speedup 1.0000x reference)
//
#include <hip/hip_runtime.h>
#include <math.h>

#define NN 512
#define FF 64
#define HH 4

// ---------------- ws layout (floats) ----------------
// dinv : [512]               off 0
// cvec : [512]               off 512
// T    : [B*H*N]   = 8192    off 1024
// q_t  : [B*H*N*F]           off 9216
// kT   : [B*H*16][N][4]      off 2106368   (feature-interleaved float4)

// S1: q/k projection. 2048 blocks x 256 thr, 2-row tiles (32 waves/CU).
//     blk -> b = blk>>9, isK = (blk>>8)&1, itile = blk&255.
//     Side jobs: dinv (blk<512, wave0), zero T (blk<128, wave1),
//     zero cvec (blk<8, wave2).
__global__ __launch_bounds__(256) void k_s1(const float* __restrict__ x,
                                            const float* __restrict__ Wq,
                                            const float* __restrict__ bq,
                                            const float* __restrict__ Wk,
                                            const float* __restrict__ bk,
                                            const float* __restrict__ adj,
                                            float* __restrict__ q_t,
                                            float* __restrict__ kT,
                                            float* __restrict__ dinv,
                                            float* __restrict__ T,
                                            float* __restrict__ cvec) {
    __shared__ float x_lds[2][64];
    int blk = blockIdx.x, tid = threadIdx.x;
    int wave = tid >> 6, lane = tid & 63;

    if (blk < 512 && wave == 0) {
        float acc = 0.f;
#pragma unroll
        for (int k = 0; k < 8; ++k) acc += adj[(long)blk * NN + k * 64 + lane];
        for (int o = 32; o > 0; o >>= 1) acc += __shfl_xor(acc, o);
        if (lane == 0) dinv[blk] = 1.0f / sqrtf(acc + 1.0f);
    }
    if (blk < 128 && wave == 1) T[blk * 64 + lane] = 0.f;
    if (blk < 8 && wave == 2) cvec[blk * 64 + lane] = 0.f;

    int b = blk >> 9, rest = blk & 511, isK = rest >> 8, itile = rest & 255;
    int i0 = itile * 2;
    if (tid < 128)
        x_lds[tid >> 6][tid & 63] = x[((long)b * NN + i0 + (tid >> 6)) * FF + (tid & 63)];
    __syncthreads();
    const float* W = isK ? Wk : Wq;
    float bv = (isK ? bk : bq)[tid];
    float a0 = bv, a1 = bv;
    for (int cc = 0; cc < 64; ++cc) {
        float w = W[cc * 256 + tid];
        a0 = fmaf(x_lds[0][cc], w, a0);
        a1 = fmaf(x_lds[1][cc], w, a1);
    }
    int h = tid >> 6, f = tid & 63;
    int bh = b * HH + h;
    if (!isK) {
        long base = ((long)bh * NN + i0) * FF + f;
        q_t[base] = a0; q_t[base + FF] = a1;
    } else {
        // kT[bh][f>>2][j][f&3], row stride 4 floats
        float* kp = kT + (((long)(bh * 16 + (f >> 2)) * NN + i0) << 2) + (f & 3);
        kp[0] = a0; kp[4] = a1;
    }
}

// S2: scores -> softmax -> noradj weighting -> atomicAdd into T (+cvec).
//     1024 blocks x 512 thr (32 waves/CU), 8 i-rows, ONE j per thread.
//     kT loads: 16 coalesced float4 per thread.
__global__ __launch_bounds__(512) void k_s2(const float* __restrict__ q_t,
                                            const float* __restrict__ kT,
                                            const float* __restrict__ adj,
                                            const float* __restrict__ dinv,
                                            float* __restrict__ T,
                                            float* __restrict__ cvec) {
    __shared__ float q_lds[8][64];
    __shared__ float red[8][8];
    __shared__ float red2[8][8];
    int blk = blockIdx.x, tid = threadIdx.x;
    int itile = blk & 63, h = (blk >> 6) & 3, b = blk >> 8;
    int bh = b * HH + h, i0 = itile * 8;
    int wv = tid >> 6, lane = tid & 63;

    q_lds[tid >> 6][tid & 63] = q_t[((long)bh * NN + i0 + (tid >> 6)) * FF + (tid & 63)];
    __syncthreads();

    int j = tid;
    const float4* kb4 = (const float4*)kT + (long)bh * 16 * NN;
    float s[8];
#pragma unroll
    for (int r = 0; r < 8; ++r) s[r] = 0.f;
#pragma unroll 4
    for (int g = 0; g < 16; ++g) {
        float4 kv = kb4[g * NN + j];
#pragma unroll
        for (int r = 0; r < 8; ++r) {
            float4 qv = *(const float4*)&q_lds[r][g * 4];
            s[r] = fmaf(qv.x, kv.x, s[r]);
            s[r] = fmaf(qv.y, kv.y, s[r]);
            s[r] = fmaf(qv.z, kv.z, s[r]);
            s[r] = fmaf(qv.w, kv.w, s[r]);
        }
    }
    const float scale = 0.125f;   // 1/sqrt(64)
#pragma unroll
    for (int r = 0; r < 8; ++r) {
        float v = s[r];
        for (int o = 32; o > 0; o >>= 1) v = fmaxf(v, __shfl_xor(v, o));
        if (lane == 0) red[r][wv] = v;
    }
    __syncthreads();
    float m[8];
#pragma unroll
    for (int r = 0; r < 8; ++r) {
        float v = red[r][0];
#pragma unroll
        for (int w = 1; w < 8; ++w) v = fmaxf(v, red[r][w]);
        m[r] = v;
    }
#pragma unroll
    for (int r = 0; r < 8; ++r) {
        s[r] = __expf((s[r] - m[r]) * scale);
        float v = s[r];
        for (int o = 32; o > 0; o >>= 1) v += __shfl_xor(v, o);
        if (lane == 0) red2[r][wv] = v;
    }
    __syncthreads();
    float Zi[8];
#pragma unroll
    for (int r = 0; r < 8; ++r) {
        float z = red2[r][0];
#pragma unroll
        for (int w = 1; w < 8; ++w) z += red2[r][w];
        Zi[r] = 1.0f / z;
    }
    float dj = dinv[j];
    float pw = 0.f, cw = 0.f;
#pragma unroll
    for (int r = 0; r < 8; ++r) {
        int gi = i0 + r;
        float di = dinv[gi];
        float a = adj[(long)gi * NN + j] + (gi == j ? 1.f : 0.f);
        float t = di * a;
        pw = fmaf(t, s[r] * Zi[r], pw);
        cw += t;
    }
    atomicAdd(&T[bh * NN + j], pw * dj);
    if (b == 0 && h == 0) atomicAdd(&cvec[j], cw);
}

// S3: fused sxd + SpMM + FC + relu. 1024 blocks x 512 thr (32 waves/CU),
//     2 rows each, 8-way j-split, LDS staging in one pass.
__global__ __launch_bounds__(512) void k_s3(const float* __restrict__ x,
                                            const float* __restrict__ T,
                                            const float* __restrict__ Wlin,
                                            const float* __restrict__ blin,
                                            const float* __restrict__ cvec,
                                            const float* __restrict__ adj,
                                            const float* __restrict__ dinv,
                                            const float* __restrict__ Wfc,
                                            const float* __restrict__ bfc,
                                            float* __restrict__ out) {
    __shared__ float4 u4_l[NN];      // dj*T[h][j], h=0..3
    __shared__ float  u0_l[NN];      // dj*dj*cvec[j]
    __shared__ float2 ad_l[NN];      // A[i0,j], A[i0+1,j] (identity folded)
    __shared__ float part[8][2][64];
    __shared__ float m_lds[2][64];
    __shared__ float part2[8][2][64];
    int blk = blockIdx.x, tid = threadIdx.x;
    int b = blk >> 8, itile = blk & 255;
    int i0 = itile * 2;

    {
        int jj = tid;   // 512 threads cover all 512 j in one pass
        float dj = dinv[jj];
        u0_l[jj] = dj * dj * cvec[jj];
        u4_l[jj] = make_float4(dj * T[(b * HH + 0) * NN + jj],
                               dj * T[(b * HH + 1) * NN + jj],
                               dj * T[(b * HH + 2) * NN + jj],
                               dj * T[(b * HH + 3) * NN + jj]);
        ad_l[jj] = make_float2(adj[(long)i0 * NN + jj] + (i0 == jj ? 1.f : 0.f),
                               adj[(long)(i0 + 1) * NN + jj] + (i0 + 1 == jj ? 1.f : 0.f));
    }
    __syncthreads();

    int f = tid & 63, jc = tid >> 6;   // jc 0..7
    int jb = jc * 64;
    float blf = blin[f];
    float4 wl = make_float4(Wlin[f], Wlin[64 + f], Wlin[128 + f], Wlin[192 + f]);
    const float* xb = x + (long)b * NN * FF + f;
    float a0 = 0.f, a1 = 0.f;
#pragma unroll 4
    for (int j = jb; j < jb + 64; ++j) {
        float xv = xb[(long)j * FF];
        float4 u = u4_l[j];
        float2 ad = ad_l[j];
        float S = blf * u0_l[j];
        S = fmaf(wl.x, u.x, S);
        S = fmaf(wl.y, u.y, S);
        S = fmaf(wl.z, u.z, S);
        S = fmaf(wl.w, u.w, S);
        float sx = xv * S;
        a0 = fmaf(ad.x, sx, a0);
        a1 = fmaf(ad.y, sx, a1);
    }
    part[jc][0][f] = a0;
    part[jc][1][f] = a1;
    __syncthreads();
    if (jc == 0) {
        float s0 = 0.f, s1 = 0.f;
#pragma unroll
        for (int c = 0; c < 8; ++c) { s0 += part[c][0][f]; s1 += part[c][1][f]; }
        m_lds[0][f] = s0 * dinv[i0];
        m_lds[1][f] = s1 * dinv[i0 + 1];
    }
    __syncthreads();
    float o0 = 0.f, o1 = 0.f;
    int c0 = jc * 8;
#pragma unroll
    for (int cc = 0; cc < 8; ++cc) {
        float w = Wfc[(c0 + cc) * FF + f];
        o0 = fmaf(m_lds[0][c0 + cc], w, o0);
        o1 = fmaf(m_lds[1][c0 + cc], w, o1);
    }
    part2[jc][0][f] = o0;
    part2[jc][1][f] = o1;
    __syncthreads();
    if (jc == 0) {
        float bb = bfc[f];
        float r0 = bb, r1 = bb;
#pragma unroll
        for (int c = 0; c < 8; ++c) { r0 += part2[c][0][f]; r1 += part2[c][1][f]; }
        out[((long)b * NN + i0) * FF + f]     = fmaxf(r0, 0.f);
        out[((long)b * NN + i0 + 1) * FF + f] = fmaxf(r1, 0.f);
    }
}

extern "C" void kernel_launch(void* const* d_in, const int* in_sizes, int n_in,
                              void* d_out, int out_size, void* d_ws, size_t ws_size,
                              hipStream_t stream) {
    const float* x    = (const float*)d_in[0];
    const float* adj  = (const float*)d_in[1];
    const float* Wq   = (const float*)d_in[2];
    const float* bq   = (const float*)d_in[3];
    const float* Wk   = (const float*)d_in[4];
    const float* bk   = (const float*)d_in[5];
    const float* Wlin = (const float*)d_in[6];
    const float* blin = (const float*)d_in[7];
    const float* Wfc  = (const float*)d_in[8];
    const float* bfc  = (const float*)d_in[9];
    float* out = (float*)d_out;

    float* ws   = (float*)d_ws;
    float* dinv = ws;                 // 512
    float* cvec = ws + 512;           // 512
    float* T    = ws + 1024;          // 8192
    float* q_t  = ws + 9216;
    float* kT   = ws + 2106368;

    k_s1<<<dim3(2048), dim3(256), 0, stream>>>(x, Wq, bq, Wk, bk, adj, q_t, kT, dinv, T, cvec);
    k_s2<<<dim3(1024), dim3(512), 0, stream>>>(q_t, kT, adj, dinv, T, cvec);
    k_s3<<<dim3(1024), dim3(512), 0, stream>>>(x, T, Wlin, blin, cvec, adj, dinv, Wfc, bfc, out);
}

// Round 13
// 108.599 us; speedup vs baseline: 1.1133x; 1.1133x over previous
//
#include <hip/hip_runtime.h>
#include <math.h>

#define NN 512
#define FF 64
#define HH 4

// ---------------- ws layout (floats) ----------------
// dinv : [512]               off 0
// cvec : [512]               off 512
// T    : [B*H*N]   = 8192    off 1024
// q_t  : [B*H][N][F]         off 9216
// kT   : [B*H][16][N][4]     off 2106368   (feature-interleaved float4)

// S1: q/k projection. 1024 blocks x 256 thr, 4-row tiles, q XOR k per block.
//     x tile transposed in LDS (xT[cc][4]) -> one b128 broadcast per cc.
//     Side jobs: dinv (blk<512 wave0), zero T (blk<128 wave1), cvec (blk<8 wave2).
__global__ __launch_bounds__(256) void k_s1(const float* __restrict__ x,
                                            const float* __restrict__ Wq,
                                            const float* __restrict__ bq,
                                            const float* __restrict__ Wk,
                                            const float* __restrict__ bk,
                                            const float* __restrict__ adj,
                                            float* __restrict__ q_t,
                                            float* __restrict__ kT,
                                            float* __restrict__ dinv,
                                            float* __restrict__ T,
                                            float* __restrict__ cvec) {
    __shared__ float xT[64][4];
    int blk = blockIdx.x, tid = threadIdx.x;
    int wave = tid >> 6, lane = tid & 63;

    if (blk < 512 && wave == 0) {
        float acc = 0.f;
#pragma unroll
        for (int k = 0; k < 8; ++k) acc += adj[(long)blk * NN + k * 64 + lane];
        for (int o = 32; o > 0; o >>= 1) acc += __shfl_xor(acc, o);
        if (lane == 0) dinv[blk] = 1.0f / sqrtf(acc + 1.0f);
    }
    if (blk < 128 && wave == 1) T[blk * 64 + lane] = 0.f;
    if (blk < 8 && wave == 2) cvec[blk * 64 + lane] = 0.f;

    int b = blk >> 8, rest = blk & 255, isK = rest >> 7, itile = rest & 127;
    int i0 = itile * 4;
    {   // coalesced read, transposed write
        int r = tid >> 6, c = tid & 63;
        xT[c][r] = x[((long)b * NN + i0 + r) * FF + c];
    }
    __syncthreads();
    const float* W = isK ? Wk : Wq;
    float bv = (isK ? bk : bq)[tid];
    float a0 = bv, a1 = bv, a2 = bv, a3 = bv;
#pragma unroll 8
    for (int cc = 0; cc < 64; ++cc) {
        float4 xr = *(const float4*)&xT[cc][0];   // b128 broadcast
        float w = W[cc * 256 + tid];              // coalesced dword
        a0 = fmaf(xr.x, w, a0);
        a1 = fmaf(xr.y, w, a1);
        a2 = fmaf(xr.z, w, a2);
        a3 = fmaf(xr.w, w, a3);
    }
    int h = tid >> 6, f = tid & 63;
    int bh = b * HH + h;
    if (!isK) {
        long base = ((long)bh * NN + i0) * FF + f;
        q_t[base] = a0; q_t[base + FF] = a1;
        q_t[base + 2 * FF] = a2; q_t[base + 3 * FF] = a3;
    } else {
        float* kp = kT + (((long)(bh * 16 + (f >> 2)) * NN + i0) << 2) + (f & 3);
        kp[0] = a0; kp[4] = a1; kp[8] = a2; kp[12] = a3;
    }
}

// S2: QK^T + softmax + noradj weighting -> T (+cvec).
//     1024 blocks (16 bh x 64 itiles of 8 rows) x 256 thr.
//     Wave w owns rows i0+2w, i0+2w+1 over ALL 512 j -> softmax is wave-local.
//     g-outer loop: q b128 broadcasts amortized over 512 j.
__global__ __launch_bounds__(256) void k_s2(const float* __restrict__ q_t,
                                            const float* __restrict__ kT,
                                            const float* __restrict__ adj,
                                            const float* __restrict__ dinv,
                                            float* __restrict__ T,
                                            float* __restrict__ cvec) {
    __shared__ float ql[8][64];
    __shared__ float pwl[4][NN];
    __shared__ float cwl[4][NN];
    int blk = blockIdx.x, tid = threadIdx.x;
    int bh = blk >> 6, itile = blk & 63;
    int i0 = itile * 8;
    int wv = tid >> 6, lane = tid & 63;

#pragma unroll
    for (int k = 0; k < 2; ++k) {
        int idx = k * 256 + tid;
        ql[idx >> 6][idx & 63] =
            q_t[((long)bh * NN + i0 + (idx >> 6)) * FF + (idx & 63)];
    }
    __syncthreads();

    int r0 = 2 * wv;
    const float4* kb4 = (const float4*)kT + (long)bh * 16 * NN;
    float s0[8], s1[8];
#pragma unroll
    for (int c = 0; c < 8; ++c) { s0[c] = 0.f; s1[c] = 0.f; }
#pragma unroll 2
    for (int g = 0; g < 16; ++g) {
        float4 q0 = *(const float4*)&ql[r0][g * 4];       // b128 broadcast
        float4 q1 = *(const float4*)&ql[r0 + 1][g * 4];
#pragma unroll
        for (int c = 0; c < 8; ++c) {
            float4 kv = kb4[g * NN + c * 64 + lane];       // coalesced b128
            s0[c] = fmaf(q0.x, kv.x, s0[c]);
            s0[c] = fmaf(q0.y, kv.y, s0[c]);
            s0[c] = fmaf(q0.z, kv.z, s0[c]);
            s0[c] = fmaf(q0.w, kv.w, s0[c]);
            s1[c] = fmaf(q1.x, kv.x, s1[c]);
            s1[c] = fmaf(q1.y, kv.y, s1[c]);
            s1[c] = fmaf(q1.z, kv.z, s1[c]);
            s1[c] = fmaf(q1.w, kv.w, s1[c]);
        }
    }
    const float scale = 0.125f;   // 1/sqrt(64)
    // wave-local row softmax
    float m0 = s0[0], m1 = s1[0];
#pragma unroll
    for (int c = 1; c < 8; ++c) { m0 = fmaxf(m0, s0[c]); m1 = fmaxf(m1, s1[c]); }
    for (int o = 32; o > 0; o >>= 1) {
        m0 = fmaxf(m0, __shfl_xor(m0, o));
        m1 = fmaxf(m1, __shfl_xor(m1, o));
    }
    float z0 = 0.f, z1 = 0.f;
#pragma unroll
    for (int c = 0; c < 8; ++c) {
        s0[c] = __expf((s0[c] - m0) * scale);
        s1[c] = __expf((s1[c] - m1) * scale);
        z0 += s0[c]; z1 += s1[c];
    }
    for (int o = 32; o > 0; o >>= 1) {
        z0 += __shfl_xor(z0, o);
        z1 += __shfl_xor(z1, o);
    }
    float Zi0 = 1.0f / z0, Zi1 = 1.0f / z1;
    int gi0 = i0 + r0, gi1 = gi0 + 1;
    float d0 = dinv[gi0] * Zi0, d1 = dinv[gi1] * Zi1;
    float e0 = dinv[gi0], e1 = dinv[gi1];
#pragma unroll
    for (int c = 0; c < 8; ++c) {
        int j = c * 64 + lane;
        float a0 = adj[(long)gi0 * NN + j] + (gi0 == j ? 1.f : 0.f);
        float a1 = adj[(long)gi1 * NN + j] + (gi1 == j ? 1.f : 0.f);
        pwl[wv][j] = fmaf(d0 * a0, s0[c], d1 * a1 * s1[c]);
        cwl[wv][j] = fmaf(e0, a0, e1 * a1);
    }
    __syncthreads();
#pragma unroll
    for (int k = 0; k < 2; ++k) {
        int j = k * 256 + tid;
        float v = pwl[0][j] + pwl[1][j] + pwl[2][j] + pwl[3][j];
        atomicAdd(&T[bh * NN + j], v * dinv[j]);
        if (bh == 0) {
            float w = cwl[0][j] + cwl[1][j] + cwl[2][j] + cwl[3][j];
            atomicAdd(&cvec[j], w);
        }
    }
}

// S3: fused sxd + SpMM + FC + relu. 256 blocks (4b x 64 itiles of 8 rows)
//     x 512 thr (8 waves, 8-way j-split of 64 j each).
//     Per-j metadata amortized over 8 rows; adj transposed adt[j][8] with
//     identity folded at staging.
__global__ __launch_bounds__(512) void k_s3(const float* __restrict__ x,
                                            const float* __restrict__ T,
                                            const float* __restrict__ Wlin,
                                            const float* __restrict__ blin,
                                            const float* __restrict__ cvec,
                                            const float* __restrict__ adj,
                                            const float* __restrict__ dinv,
                                            const float* __restrict__ Wfc,
                                            const float* __restrict__ bfc,
                                            float* __restrict__ out) {
    __shared__ float4 u4_l[NN];       // dj*T[h][j]
    __shared__ float  u0_l[NN];       // dj*dj*cvec[j]
    __shared__ float  adt[NN][8];     // A^T tile, identity folded
    __shared__ float  part[8][8][64];
    __shared__ float  m_lds[8][64];
    int blk = blockIdx.x, tid = threadIdx.x;
    int b = blk >> 6, itile = blk & 63;
    int i0 = itile * 8;

    {   // staging: one j per thread
        int jj = tid;
        float dj = dinv[jj];
        u0_l[jj] = dj * dj * cvec[jj];
        const float* Tb = T + (long)b * HH * NN;
        u4_l[jj] = make_float4(dj * Tb[jj], dj * Tb[NN + jj],
                               dj * Tb[2 * NN + jj], dj * Tb[3 * NN + jj]);
        float av[8];
#pragma unroll
        for (int r = 0; r < 8; ++r)
            av[r] = adj[(long)(i0 + r) * NN + jj] + (i0 + r == jj ? 1.f : 0.f);
        *(float4*)&adt[jj][0] = make_float4(av[0], av[1], av[2], av[3]);
        *(float4*)&adt[jj][4] = make_float4(av[4], av[5], av[6], av[7]);
    }
    __syncthreads();

    int f = tid & 63, jc = tid >> 6;   // jc 0..7
    int jb = jc * 64;
    float blf = blin[f];
    float4 wl = make_float4(Wlin[f], Wlin[64 + f], Wlin[128 + f], Wlin[192 + f]);
    const float* xb = x + (long)b * NN * FF + f;
    float a[8];
#pragma unroll
    for (int r = 0; r < 8; ++r) a[r] = 0.f;
#pragma unroll 4
    for (int j = jb; j < jb + 64; ++j) {
        float xv = xb[(long)j * FF];
        float4 u = u4_l[j];
        float S = blf * u0_l[j];
        S = fmaf(wl.x, u.x, S);
        S = fmaf(wl.y, u.y, S);
        S = fmaf(wl.z, u.z, S);
        S = fmaf(wl.w, u.w, S);
        float sx = xv * S;
        float4 t0 = *(const float4*)&adt[j][0];
        float4 t1 = *(const float4*)&adt[j][4];
        a[0] = fmaf(t0.x, sx, a[0]);
        a[1] = fmaf(t0.y, sx, a[1]);
        a[2] = fmaf(t0.z, sx, a[2]);
        a[3] = fmaf(t0.w, sx, a[3]);
        a[4] = fmaf(t1.x, sx, a[4]);
        a[5] = fmaf(t1.y, sx, a[5]);
        a[6] = fmaf(t1.z, sx, a[6]);
        a[7] = fmaf(t1.w, sx, a[7]);
    }
#pragma unroll
    for (int r = 0; r < 8; ++r) part[jc][r][f] = a[r];
    __syncthreads();

    {   // combine: one (row, f) per thread
        int r = tid >> 6;
        float s = 0.f;
#pragma unroll
        for (int c = 0; c < 8; ++c) s += part[c][r][f];
        m_lds[r][f] = s * dinv[i0 + r];
    }
    __syncthreads();
    {   // FC + relu: one (row, f) per thread
        int r = tid >> 6;
        float o = bfc[f];
#pragma unroll 8
        for (int cc = 0; cc < 64; ++cc)
            o = fmaf(m_lds[r][cc], Wfc[cc * FF + f], o);
        out[((long)b * NN + i0 + r) * FF + f] = fmaxf(o, 0.f);
    }
}

extern "C" void kernel_launch(void* const* d_in, const int* in_sizes, int n_in,
                              void* d_out, int out_size, void* d_ws, size_t ws_size,
                              hipStream_t stream) {
    const float* x    = (const float*)d_in[0];
    const float* adj  = (const float*)d_in[1];
    const float* Wq   = (const float*)d_in[2];
    const float* bq   = (const float*)d_in[3];
    const float* Wk   = (const float*)d_in[4];
    const float* bk   = (const float*)d_in[5];
    const float* Wlin = (const float*)d_in[6];
    const float* blin = (const float*)d_in[7];
    const float* Wfc  = (const float*)d_in[8];
    const float* bfc  = (const float*)d_in[9];
    float* out = (float*)d_out;

    float* ws   = (float*)d_ws;
    float* dinv = ws;                 // 512
    float* cvec = ws + 512;           // 512
    float* T    = ws + 1024;          // 8192
    float* q_t  = ws + 9216;
    float* kT   = ws + 2106368;

    k_s1<<<dim3(1024), dim3(256), 0, stream>>>(x, Wq, bq, Wk, bk, adj, q_t, kT, dinv, T, cvec);
    k_s2<<<dim3(1024), dim3(256), 0, stream>>>(q_t, kT, adj, dinv, T, cvec);
    k_s3<<<dim3(256), dim3(512), 0, stream>>>(x, T, Wlin, blin, cvec, adj, dinv, Wfc, bfc, out);
}